// Round 7
// baseline (296.276 us; speedup 1.0000x reference)
//
#include <hip/hip_runtime.h>
#include <hip/hip_bf16.h>

#define NLOG 16
#define NN 65536
#define KK 9
#define FF 32
#define OO 64
#define DD 288            // K*F
#define WSTR 296          // padded W row stride (shorts)
#define CHUNK 64          // points per block-chunk
#define THREADS 256
#define NBLOCKS 1024
#define NXCD 8
#define SLOTS (NBLOCKS / NXCD)    // 128 blocks per XCD
#define CPB (NN / CHUNK)          // 1024 chunks per batch
#define JROUNDS (CPB / SLOTS)     // 8 chunks per block
#define TOTALP (8 * NN)
#define RA_STRIDE 72              // shorts/point: 9 t-rows x 8 bf16 (16B rows)
#define RB_STRIDE 10              // shorts/point: k=8 column over t, +1 pad

typedef float f32x4 __attribute__((ext_vector_type(4)));
typedef unsigned int u32x4 __attribute__((ext_vector_type(4)));
typedef short s16x8 __attribute__((ext_vector_type(8)));
typedef short s16x4 __attribute__((ext_vector_type(4)));

static __device__ __forceinline__ short f2bf(float f) {
    union { __hip_bfloat16 h; short s; } u;
    u.h = __float2bfloat16(f);
    return u.s;
}

// exact bf16->f32
static __device__ __forceinline__ void bf2f2(unsigned int p, float& lo, float& hi) {
    union { unsigned int u; float f; } a, b;
    a.u = p << 16;
    b.u = p & 0xFFFF0000u;
    lo = a.f; hi = b.f;
}
static __device__ __forceinline__ float bf1(unsigned short s) {
    union { unsigned int u; float f; } a;
    a.u = ((unsigned int)s) << 16;
    return a.f;
}

static __device__ __forceinline__ float elu1(float x) {
    float e = __expf(fminf(x, 0.f)) - 1.f;
    return x > 0.f ? x : e;
}

// ---- pre-kernel 1: x (f32) -> xbf (bf16), same layout ----
__global__ __launch_bounds__(THREADS) void xcvt(
    const float* __restrict__ x, unsigned short* __restrict__ xbf)
{
    const size_t i = ((size_t)blockIdx.x * THREADS + threadIdx.x) * 8;
    const f32x4 a = *(const f32x4*)(x + i);
    const f32x4 b = *(const f32x4*)(x + i + 4);
    s16x8 p;
    p[0] = f2bf(a.x); p[1] = f2bf(a.y); p[2] = f2bf(a.z); p[3] = f2bf(a.w);
    p[4] = f2bf(b.x); p[5] = f2bf(b.y); p[6] = f2bf(b.z); p[7] = f2bf(b.w);
    *(s16x8*)(xbf + i) = p;
}

// ---- pre-kernel 2: adjacency -> packed bf16 (recA: k=0..7, recB: k=8) ----
__global__ __launch_bounds__(THREADS) void adjcvt(
    const float* __restrict__ v, const float* __restrict__ aw,
    unsigned short* __restrict__ recA, unsigned short* __restrict__ recB)
{
    const int e = blockIdx.x * THREADS + threadIdx.x;   // over NN*KK exact
    const int n = e / KK;
    const int t = e - n * KK;
    const float* vr = v + n * 8;
    short o[8];
    float s8 = 0.f;
    #pragma unroll
    for (int k = 0; k < KK; ++k) {
        float s = 0.f;
        #pragma unroll
        for (int si = 0; si < 8; ++si)
            s += vr[si] * aw[si * 81 + k * 9 + t];
        if (k < 8) o[k] = f2bf(s); else s8 = s;
    }
    *(s16x8*)(recA + (size_t)n * RA_STRIDE + t * 8) = *(s16x8*)o;
    recB[(size_t)n * RB_STRIDE + t] = (unsigned short)f2bf(s8);
    if (t == 0) recB[(size_t)n * RB_STRIDE + 9] = 0;
}

// ---- main kernel ----
// XCD-pinned batches: HW round-robins blockIdx%8 across XCDs -> batch q is
// processed ONLY by XCD q, whose 4 MB L2 keeps that batch's 4.2 MB bf16 x
// resident for the whole kernel (gather = L2 hits after compulsory fills).
// R4's bf16-x failed WITHOUT pinning (set re-evicted every round under
// stream pressure). Streams (adj/nbr/out) are read/write-once per XCD.
// __launch_bounds__(256,2): ",4" caps VGPR below live G[9][8] -> spills (R2).
// No nontemporal (R5: nt stores 2x write amp; nt sub-line loads inflate fetch).
template<bool PRE>
__global__ __launch_bounds__(THREADS, 2) void paiconv_main(
    const float* __restrict__ x,
    const unsigned short* __restrict__ xbf,
    const int* __restrict__ nbr,
    const float* __restrict__ v,
    const float* __restrict__ aw,
    const unsigned short* __restrict__ recA,
    const unsigned short* __restrict__ recB,
    const float* __restrict__ W,
    const float* __restrict__ bias,
    float* __restrict__ out)
{
    __shared__ short Wl[OO * WSTR];     // 37888 B
    __shared__ float BL[OO];            // -> 4 blocks/CU

    const int tid = threadIdx.x;

    // stage W (fp32 global -> bf16 LDS), once per block
    for (int e = tid; e < OO * DD / 4; e += THREADS) {
        int o = e / 72;
        int d4 = (e - o * 72) * 4;
        const f32x4 wv = *(const f32x4*)(W + o * DD + d4);
        s16x4 p;
        p.x = f2bf(wv.x); p.y = f2bf(wv.y); p.z = f2bf(wv.z); p.w = f2bf(wv.w);
        *(s16x4*)(&Wl[o * WSTR + d4]) = p;
    }
    if (tid < OO) BL[tid] = bias[tid];
    __syncthreads();                    // only barrier in the kernel

    const int lane = tid & 63;
    const int wid  = tid >> 6;
    const int l15  = lane & 15;       // A row (point in 16-tile) / C col (o in 16-group)
    const int fg   = lane >> 4;       // octet group
    const int fo   = fg * 8;          // f offset of this lane's octet
    const int pl   = wid * 16 + l15;  // point within chunk

    const int q    = blockIdx.x & (NXCD - 1);  // batch == XCD id
    const int slot = blockIdx.x >> 3;          // 0..127

    for (int j = 0; j < JROUNDS; ++j) {
        const int cl = slot + j * SLOTS;       // chunk within batch, 0..1023
        const int cbase = cl * CHUNK;          // vertex base
        const int n = cbase + pl;              // vertex id of this lane's point
        const int P = (q << NLOG) + n;         // flat point id
        const int* nip = nbr + (size_t)P * KK;

        // gather neighbor features: G[k][j] = x[q, idx[k], fo+j]
        float G[KK][8];
        if (PRE) {
            const unsigned short* xb = xbf + (((size_t)q) << NLOG) * FF;
            #pragma unroll
            for (int k = 0; k < KK; ++k) {
                const int row = nip[k];
                const u32x4 g = *(const u32x4*)(xb + (size_t)row * FF + fo);
                bf2f2(g.x, G[k][0], G[k][1]);
                bf2f2(g.y, G[k][2], G[k][3]);
                bf2f2(g.z, G[k][4], G[k][5]);
                bf2f2(g.w, G[k][6], G[k][7]);
            }
        } else {
            const float* xb = x + (((size_t)q) << NLOG) * FF;
            #pragma unroll
            for (int k = 0; k < KK; ++k) {
                const float* src = xb + (size_t)nip[k] * FF + fo;
                f32x4 g0 = *(const f32x4*)(src);
                f32x4 g1 = *(const f32x4*)(src + 4);
                G[k][0] = g0.x; G[k][1] = g0.y; G[k][2] = g0.z; G[k][3] = g0.w;
                G[k][4] = g1.x; G[k][5] = g1.y; G[k][6] = g1.z; G[k][7] = g1.w;
            }
        }

        float vr[8];
        if (!PRE) {
            #pragma unroll
            for (int si = 0; si < 8; ++si) vr[si] = v[n * 8 + si];
        }

        f32x4 acc0 = {0.f, 0.f, 0.f, 0.f};
        f32x4 acc1 = {0.f, 0.f, 0.f, 0.f};
        f32x4 acc2 = {0.f, 0.f, 0.f, 0.f};
        f32x4 acc3 = {0.f, 0.f, 0.f, 0.f};

        const unsigned short* ra = recA + (size_t)n * RA_STRIDE;
        const unsigned short* rb = recB + (size_t)n * RB_STRIDE;

        #pragma unroll
        for (int t = 0; t < KK; ++t) {
            float a[KK];
            if (PRE) {
                const u32x4 qv = *(const u32x4*)(ra + t * 8);   // 16B aligned
                bf2f2(qv.x, a[0], a[1]);
                bf2f2(qv.y, a[2], a[3]);
                bf2f2(qv.z, a[4], a[5]);
                bf2f2(qv.w, a[6], a[7]);
                a[8] = bf1(rb[t]);
            } else {
                #pragma unroll
                for (int k = 0; k < KK; ++k) {
                    float s = 0.f;
                    #pragma unroll
                    for (int si = 0; si < 8; ++si)
                        s += vr[si] * aw[si * 81 + k * 9 + t];
                    a[k] = s;
                }
            }

            float xn[8] = {0.f, 0.f, 0.f, 0.f, 0.f, 0.f, 0.f, 0.f};
            #pragma unroll
            for (int k = 0; k < KK; ++k) {
                #pragma unroll
                for (int jj = 0; jj < 8; ++jj) xn[jj] += G[k][jj] * a[k];
            }
            s16x8 af;
            #pragma unroll
            for (int jj = 0; jj < 8; ++jj) af[jj] = f2bf(elu1(xn[jj]));

            const short* wrow = &Wl[l15 * WSTR + t * FF + fo];
            s16x8 b0 = *(const s16x8*)(wrow);
            s16x8 b1 = *(const s16x8*)(wrow + 16 * WSTR);
            s16x8 b2 = *(const s16x8*)(wrow + 32 * WSTR);
            s16x8 b3 = *(const s16x8*)(wrow + 48 * WSTR);
            acc0 = __builtin_amdgcn_mfma_f32_16x16x32_bf16(af, b0, acc0, 0, 0, 0);
            acc1 = __builtin_amdgcn_mfma_f32_16x16x32_bf16(af, b1, acc1, 0, 0, 0);
            acc2 = __builtin_amdgcn_mfma_f32_16x16x32_bf16(af, b2, acc2, 0, 0, 0);
            acc3 = __builtin_amdgcn_mfma_f32_16x16x32_bf16(af, b3, acc3, 0, 0, 0);
        }

        // epilogue: bias + elu + padding mask + store (C: col=l15, row=fg*4+r)
        #pragma unroll
        for (int ot = 0; ot < 4; ++ot) {
            const f32x4 a = (ot == 0) ? acc0 : (ot == 1) ? acc1 : (ot == 2) ? acc2 : acc3;
            const int o = ot * 16 + l15;
            const float bv = BL[o];
            #pragma unroll
            for (int r = 0; r < 4; ++r) {
                const int nn2 = cbase + wid * 16 + fg * 4 + r;     // vertex id
                float val = elu1(a[r] + bv);
                if (nn2 == NN - 1) val = 0.f;
                out[(((size_t)q << NLOG) + nn2) * OO + o] = val;
            }
        }
    }
}

extern "C" void kernel_launch(void* const* d_in, const int* in_sizes, int n_in,
                              void* d_out, int out_size, void* d_ws, size_t ws_size,
                              hipStream_t stream) {
    const float* x    = (const float*)d_in[0];
    // d_in[1] = t_vertex (unused in forward)
    const int*   nbr  = (const int*)d_in[2];
    const float* v    = (const float*)d_in[3];
    const float* aw   = (const float*)d_in[4];
    const float* W    = (const float*)d_in[5];
    const float* bias = (const float*)d_in[6];
    float* out = (float*)d_out;

    const size_t xbf_bytes = (size_t)TOTALP * FF * 2;     // 33,554,432
    const size_t ra_bytes  = (size_t)NN * RA_STRIDE * 2;  //  9,437,184
    const size_t rb_bytes  = (size_t)NN * RB_STRIDE * 2;  //  1,310,720
    const size_t need = xbf_bytes + ra_bytes + rb_bytes;  // ~44 MiB

    if (ws_size >= need) {
        unsigned short* xbf  = (unsigned short*)d_ws;
        unsigned short* recA = (unsigned short*)((char*)d_ws + xbf_bytes);
        unsigned short* recB = (unsigned short*)((char*)d_ws + xbf_bytes + ra_bytes);
        hipLaunchKernelGGL(xcvt, dim3((TOTALP * FF / 8) / THREADS), dim3(THREADS),
                           0, stream, x, xbf);
        hipLaunchKernelGGL(adjcvt, dim3((NN * KK) / THREADS), dim3(THREADS),
                           0, stream, v, aw, recA, recB);
        hipLaunchKernelGGL((paiconv_main<true>), dim3(NBLOCKS), dim3(THREADS), 0, stream,
                           x, xbf, nbr, v, aw, recA, recB, W, bias, out);
    } else {
        hipLaunchKernelGGL((paiconv_main<false>), dim3(NBLOCKS), dim3(THREADS), 0, stream,
                           x, (const unsigned short*)nullptr, nbr, v, aw,
                           (const unsigned short*)nullptr, (const unsigned short*)nullptr,
                           W, bias, out);
    }
}

// Round 8
// 230.726 us; speedup vs baseline: 1.2841x; 1.2841x over previous
//
#include <hip/hip_runtime.h>
#include <hip/hip_bf16.h>

#define NLOG 16
#define NN 65536
#define KK 9
#define FF 32
#define OO 64
#define DD 288            // K*F
#define WSTR 296          // padded W row stride (shorts)
#define CHUNK 64          // points per block-chunk
#define THREADS 256
#define NBLOCKS 1024
#define TOTALP (8 * NN)           // 524288
#define NCHUNKS (TOTALP / CHUNK)  // 8192
#define RA_STRIDE 72              // shorts/point: 9 t-rows x 8 bf16 (16B rows)
#define RB_STRIDE 10              // shorts/point: k=8 column over t, +1 pad

typedef float f32x4 __attribute__((ext_vector_type(4)));
typedef float f32x2 __attribute__((ext_vector_type(2)));
typedef unsigned int u32x4 __attribute__((ext_vector_type(4)));
typedef short s16x8 __attribute__((ext_vector_type(8)));
typedef short s16x4 __attribute__((ext_vector_type(4)));

static __device__ __forceinline__ short f2bf(float f) {
    union { __hip_bfloat16 h; short s; } u;
    u.h = __float2bfloat16(f);
    return u.s;
}

// exact bf16->f32
static __device__ __forceinline__ void bf2f2(unsigned int p, float& lo, float& hi) {
    union { unsigned int u; float f; } a, b;
    a.u = p << 16;
    b.u = p & 0xFFFF0000u;
    lo = a.f; hi = b.f;
}
static __device__ __forceinline__ float bf1(unsigned short s) {
    union { unsigned int u; float f; } a;
    a.u = ((unsigned int)s) << 16;
    return a.f;
}

static __device__ __forceinline__ float elu1(float x) {
    float e = __expf(fminf(x, 0.f)) - 1.f;
    return x > 0.f ? x : e;
}

// ---- pre-kernel: adjacency -> packed bf16 (recA: k=0..7, recB: k=8) ----
__global__ __launch_bounds__(THREADS) void adjcvt(
    const float* __restrict__ v, const float* __restrict__ aw,
    unsigned short* __restrict__ recA, unsigned short* __restrict__ recB)
{
    const int e = blockIdx.x * THREADS + threadIdx.x;   // over NN*KK exact
    const int n = e / KK;
    const int t = e - n * KK;
    const float* vr = v + n * 8;
    short o[8];
    float s8 = 0.f;
    #pragma unroll
    for (int k = 0; k < KK; ++k) {
        float s = 0.f;
        #pragma unroll
        for (int si = 0; si < 8; ++si)
            s += vr[si] * aw[si * 81 + k * 9 + t];
        if (k < 8) o[k] = f2bf(s); else s8 = s;
    }
    *(s16x8*)(recA + (size_t)n * RA_STRIDE + t * 8) = *(s16x8*)o;
    recB[(size_t)n * RB_STRIDE + t] = (unsigned short)f2bf(s8);
    if (t == 0) recB[(size_t)n * RB_STRIDE + 9] = 0;
}

// ---- main kernel (R6 baseline + swapped-MFMA vectorized epilogue) ----
// Structure notes (hard-won):
//  * Grid-stride over chunks, UNPINNED: all XCDs time-correlated on one batch
//    -> 8.4MB fp32 slice lives in 32MB aggregate L2 (~45% gather hit). Pinning
//    (R7) thrashes the 4MB per-XCD L2 (4.19MB bf16 slice + streams) -> 0% hit.
//  * fp32 x gather: full 128B line per row; bf16 rows waste half of each fill
//    granule (R4/R7).
//  * NO nontemporal (R5: nt stores 2x write amp; nt loads refetch).
//  * __launch_bounds__(256,2): ",4" caps VGPR below live G[9][8] -> spills (R2).
//  * Swapped MFMA (A=W, B=xn; validated R5): lane's C-frag = contiguous
//    o-nibble -> 4x f32x4 stores per lane (full 64B sectors) instead of
//    16 scalar stores.
template<bool PRE>
__global__ __launch_bounds__(THREADS, 2) void paiconv_main(
    const float* __restrict__ x,
    const int* __restrict__ nbr,
    const float* __restrict__ v,
    const float* __restrict__ aw,
    const unsigned short* __restrict__ recA,
    const unsigned short* __restrict__ recB,
    const float* __restrict__ W,
    const float* __restrict__ bias,
    float* __restrict__ out)
{
    __shared__ short Wl[OO * WSTR];     // 37888 B
    __shared__ float BL[OO];            // -> 4 blocks/CU

    const int tid = threadIdx.x;

    // stage W (fp32 global -> bf16 LDS), once per block
    for (int e = tid; e < OO * DD / 4; e += THREADS) {
        int o = e / 72;
        int d4 = (e - o * 72) * 4;
        const f32x4 wv = *(const f32x4*)(W + o * DD + d4);
        s16x4 p;
        p.x = f2bf(wv.x); p.y = f2bf(wv.y); p.z = f2bf(wv.z); p.w = f2bf(wv.w);
        *(s16x4*)(&Wl[o * WSTR + d4]) = p;
    }
    if (tid < OO) BL[tid] = bias[tid];
    __syncthreads();                    // only barrier in the kernel

    const int lane = tid & 63;
    const int wid  = tid >> 6;
    const int l15  = lane & 15;       // point within 16-tile (B-col) / W-row (A)
    const int fg   = lane >> 4;       // octet group
    const int fo   = fg * 8;          // f offset of this lane's octet
    const int pl   = wid * 16 + l15;  // point within chunk

    for (int ci = blockIdx.x; ci < NCHUNKS; ci += NBLOCKS) {
        const int cbase = ci * CHUNK;
        const int P = cbase + pl;
        const int n = P & (NN - 1);
        const int b = P >> NLOG;
        const int* nip = nbr + (size_t)P * KK;
        const float* xb = x + (((size_t)b) << NLOG) * FF;

        // gather neighbor features: G2[k][i] = x[b, idx[k], fo+2i..2i+1]
        f32x2 G2[KK][4];
        #pragma unroll
        for (int k = 0; k < KK; ++k) {
            const int row = nip[k];
            const float* src = xb + (size_t)row * FF + fo;
            const f32x4 g0 = *(const f32x4*)(src);
            const f32x4 g1 = *(const f32x4*)(src + 4);
            G2[k][0] = f32x2{g0.x, g0.y};
            G2[k][1] = f32x2{g0.z, g0.w};
            G2[k][2] = f32x2{g1.x, g1.y};
            G2[k][3] = f32x2{g1.z, g1.w};
        }

        float vr[8];
        if (!PRE) {
            #pragma unroll
            for (int si = 0; si < 8; ++si) vr[si] = v[n * 8 + si];
        }

        f32x4 acc0 = {0.f, 0.f, 0.f, 0.f};
        f32x4 acc1 = {0.f, 0.f, 0.f, 0.f};
        f32x4 acc2 = {0.f, 0.f, 0.f, 0.f};
        f32x4 acc3 = {0.f, 0.f, 0.f, 0.f};

        const unsigned short* ra = recA + (size_t)n * RA_STRIDE;
        const unsigned short* rb = recB + (size_t)n * RB_STRIDE;

        #pragma unroll
        for (int t = 0; t < KK; ++t) {
            float a[KK];
            if (PRE) {
                const u32x4 qv = *(const u32x4*)(ra + t * 8);   // 16B aligned
                bf2f2(qv.x, a[0], a[1]);
                bf2f2(qv.y, a[2], a[3]);
                bf2f2(qv.z, a[4], a[5]);
                bf2f2(qv.w, a[6], a[7]);
                a[8] = bf1(rb[t]);
            } else {
                #pragma unroll
                for (int k = 0; k < KK; ++k) {
                    float s = 0.f;
                    #pragma unroll
                    for (int si = 0; si < 8; ++si)
                        s += vr[si] * aw[si * 81 + k * 9 + t];
                    a[k] = s;
                }
            }

            // xn contraction in f32x2 (nudges v_pk_fma_f32)
            f32x2 xn2[4] = {{0.f,0.f},{0.f,0.f},{0.f,0.f},{0.f,0.f}};
            #pragma unroll
            for (int k = 0; k < KK; ++k) {
                const f32x2 ak = {a[k], a[k]};
                #pragma unroll
                for (int i = 0; i < 4; ++i) xn2[i] += G2[k][i] * ak;
            }
            s16x8 af;
            #pragma unroll
            for (int i = 0; i < 4; ++i) {
                af[2*i]   = f2bf(elu1(xn2[i].x));
                af[2*i+1] = f2bf(elu1(xn2[i].y));
            }

            const short* wrow = &Wl[l15 * WSTR + t * FF + fo];
            s16x8 b0 = *(const s16x8*)(wrow);
            s16x8 b1 = *(const s16x8*)(wrow + 16 * WSTR);
            s16x8 b2 = *(const s16x8*)(wrow + 32 * WSTR);
            s16x8 b3 = *(const s16x8*)(wrow + 48 * WSTR);
            // swapped: A = W tile (row=o within 16-group), B = xn (col=point)
            acc0 = __builtin_amdgcn_mfma_f32_16x16x32_bf16(b0, af, acc0, 0, 0, 0);
            acc1 = __builtin_amdgcn_mfma_f32_16x16x32_bf16(b1, af, acc1, 0, 0, 0);
            acc2 = __builtin_amdgcn_mfma_f32_16x16x32_bf16(b2, af, acc2, 0, 0, 0);
            acc3 = __builtin_amdgcn_mfma_f32_16x16x32_bf16(b3, af, acc3, 0, 0, 0);
        }

        // epilogue: C col(l15)=point P, row(fg*4+reg)=o within 16-group ot.
        // per-lane contiguous f32x4 (o-nibble) CACHED store; per-lane mask.
        const bool zero_pt = ((P & (NN - 1)) == (NN - 1));
        float* orow = out + (size_t)P * OO + fg * 4;
        #pragma unroll
        for (int ot = 0; ot < 4; ++ot) {
            const f32x4 a = (ot == 0) ? acc0 : (ot == 1) ? acc1 : (ot == 2) ? acc2 : acc3;
            const f32x4 bv = *(const f32x4*)&BL[ot * 16 + fg * 4];
            f32x4 r;
            #pragma unroll
            for (int j = 0; j < 4; ++j)
                r[j] = zero_pt ? 0.f : elu1(a[j] + bv[j]);
            *(f32x4*)(orow + ot * 16) = r;
        }
    }
}

extern "C" void kernel_launch(void* const* d_in, const int* in_sizes, int n_in,
                              void* d_out, int out_size, void* d_ws, size_t ws_size,
                              hipStream_t stream) {
    const float* x    = (const float*)d_in[0];
    // d_in[1] = t_vertex (unused in forward)
    const int*   nbr  = (const int*)d_in[2];
    const float* v    = (const float*)d_in[3];
    const float* aw   = (const float*)d_in[4];
    const float* W    = (const float*)d_in[5];
    const float* bias = (const float*)d_in[6];
    float* out = (float*)d_out;

    const size_t ra_bytes = (size_t)NN * RA_STRIDE * 2;   // 9,437,184
    const size_t rb_bytes = (size_t)NN * RB_STRIDE * 2;   // 1,310,720
    const size_t need = ra_bytes + rb_bytes;              // ~10.8 MB

    if (ws_size >= need) {
        unsigned short* recA = (unsigned short*)d_ws;
        unsigned short* recB = (unsigned short*)((char*)d_ws + ra_bytes);
        hipLaunchKernelGGL(adjcvt, dim3((NN * KK) / THREADS), dim3(THREADS),
                           0, stream, v, aw, recA, recB);
        hipLaunchKernelGGL((paiconv_main<true>), dim3(NBLOCKS), dim3(THREADS), 0, stream,
                           x, nbr, v, aw, recA, recB, W, bias, out);
    } else {
        hipLaunchKernelGGL((paiconv_main<false>), dim3(NBLOCKS), dim3(THREADS), 0, stream,
                           x, nbr, v, aw,
                           (const unsigned short*)nullptr, (const unsigned short*)nullptr,
                           W, bias, out);
    }
}